// Round 2
// baseline (1231.273 us; speedup 1.0000x reference)
//
#include <hip/hip_runtime.h>
#include <hip/hip_bf16.h>

// GPNN_HICO: B=4, N=256, EDGE_F=256, MSG=128, LINK_H=128, ROUNDS=3, CLASSES=600
// Algebra:
//  - only the valid[b] x valid[b] block of any [N,N] tensor matters
//  - m_raw is round-invariant (reference never writes node state back)
//  - e_state_r[b,i,w] (valid block) = sigmoid(s_{r-1}[b,w,i]) * m_raw[b,w,i]
// Dtype of the external tensors is detected on-device (bf16 vs fp32); all
// compute kernels are templated on IS_BF16 and launched in both flavors with
// a device-flag early-exit.

#define B_ 4
#define N_ 256
#define EF_ 256
#define M_ 128
#define CL_ 600
#define ADJ_SZ (B_*N_*N_)

typedef __hip_bfloat16 bf16;

__device__ __forceinline__ float b2f(bf16 x){ return __bfloat162float(x); }
__device__ __forceinline__ bf16  f2b(float x){ return __float2bfloat16(x); }
__device__ __forceinline__ float sigm(float x){ return 1.0f/(1.0f+expf(-x)); }

template<bool BF>
__device__ __forceinline__ float ld(const void* p, size_t i){
  if (BF) return b2f(((const bf16*)p)[i]);
  else    return ((const float*)p)[i];
}
template<bool BF>
__device__ __forceinline__ void st(void* p, size_t i, float v){
  if (BF) ((bf16*)p)[i] = f2b(v);
  else    ((float*)p)[i] = v;
}

// ---- dtype detector: bf16 buffers have ~100% sane exponent fields; fp32
// buffers read as uint16 have ~59% (low halves are uniform random). ----
__global__ __launch_bounds__(64)
void k_detect(const unsigned short* ef, int* flag){
  int t = threadIdx.x;
  int cnt = 0;
  for (int j = 0; j < 64; j++){
    unsigned short u = ef[t*64 + j];
    int e = (u >> 7) & 0xFF;
    cnt += (e >= 96 && e <= 144) ? 1 : 0;
  }
  for (int o = 32; o > 0; o >>= 1) cnt += __shfl_down(cnt, o, 64);
  if (t == 0) *flag = (cnt > 3500) ? 1 : 0;
}

template<bool BF>
__global__ __launch_bounds__(256)
void k_zero(void* out, int n, const int* dflag){
  if ((*dflag != 0) != BF) return;
  int i = blockIdx.x*256 + threadIdx.x;
  if (i < n) st<BF>(out, i, 0.0f);
}

// nf[b,v,:] = node_features @ W_nr + b_nr ; cb[b,v,:] = b_msg + nf @ W_msg[0:128,:]
template<bool BF>
__global__ __launch_bounds__(128)
void k_nf_c(const void* nodef, const void* W_nr, const void* b_nr,
            const void* W_msg, const void* b_msg, float* nf, float* cb,
            const int* dflag)
{
  if ((*dflag != 0) != BF) return;
  int blk = blockIdx.x; int b = blk >> 8; int v = blk & 255;
  int t = threadIdx.x;  // 128
  __shared__ float xs[EF_];
  __shared__ float nfs[M_];
  size_t xrow = ((size_t)(b*N_)+v)*EF_;
  xs[t]     = ld<BF>(nodef, xrow + t);
  xs[t+128] = ld<BF>(nodef, xrow + t + 128);
  __syncthreads();
  float acc = ld<BF>(b_nr, t);
  for (int k=0;k<EF_;k++) acc += xs[k]*ld<BF>(W_nr, (size_t)k*M_+t);
  nf[((size_t)(b*N_)+v)*M_+t] = acc;
  nfs[t] = acc;
  __syncthreads();
  float acc2 = ld<BF>(b_msg, t);
  for (int k=0;k<M_;k++) acc2 += nfs[k]*ld<BF>(W_msg, (size_t)k*M_+t);
  cb[((size_t)(b*N_)+v)*M_+t] = acc2;
}

// Fused round 0 per (b, i, w-tile of 8) in valid block:
//   ef = edge @ W_er + b_er ; mraw = relu(cb[b,w] + ef @ W_msg[128:,:]) (bf16)
//   s0 = relu(ef @ W_l1 + b_l1) @ W_l2 + b_l2
template<bool BF>
__global__ __launch_bounds__(256)
void k_ef_mraw_s0(const void* edgef, const void* W_er, const void* b_er,
                  const void* W_msg, const float* cb,
                  const void* W_l1, const void* b_l1,
                  const void* W_l2, const void* b_l2,
                  const int* hn, const int* on, bf16* mraw, float* s0,
                  const int* dflag)
{
  if ((*dflag != 0) != BF) return;
  int b = blockIdx.z, i = blockIdx.y, w0 = blockIdx.x*8;
  int valid = hn[b] + on[b];
  if (i >= valid || w0 >= valid) return;
  int t = threadIdx.x, ch = t & 127, half = t >> 7;
  __shared__ float xs[8][EF_];
  __shared__ float part[2][8][M_];
  __shared__ float efs[8][M_];
  __shared__ float hl[8][M_];
  size_t ebase = (((size_t)(b*N_)+i)*N_+w0)*EF_;
  #pragma unroll
  for (int j=0;j<8;j++){
    float v = 0.f;
    if (w0+j < valid) v = ld<BF>(edgef, ebase + (size_t)j*EF_ + t);
    xs[j][t] = v;
  }
  __syncthreads();
  float acc[8];
  #pragma unroll
  for (int j=0;j<8;j++) acc[j] = (half==0) ? ld<BF>(b_er, ch) : 0.f;
  for (int k=half*128; k<half*128+128; k++){
    float wv = ld<BF>(W_er, (size_t)k*M_+ch);
    #pragma unroll
    for (int j=0;j<8;j++) acc[j] += xs[j][k]*wv;
  }
  #pragma unroll
  for (int j=0;j<8;j++) part[half][j][ch] = acc[j];
  __syncthreads();
  for (int idx=t; idx<8*M_; idx+=256){
    int j = idx>>7, cc = idx&127;
    efs[j][cc] = part[0][j][cc] + part[1][j][cc];
  }
  __syncthreads();
  #pragma unroll
  for (int j=0;j<8;j++) acc[j] = 0.f;
  for (int k=half*64; k<half*64+64; k++){
    float wv = ld<BF>(W_msg, (size_t)(128+k)*M_+ch);
    #pragma unroll
    for (int j=0;j<8;j++) acc[j] += efs[j][k]*wv;
  }
  #pragma unroll
  for (int j=0;j<8;j++) part[half][j][ch] = acc[j];
  __syncthreads();
  for (int idx=t; idx<8*M_; idx+=256){
    int j = idx>>7, cc = idx&127; int w = w0+j;
    if (w < valid){
      float v = part[0][j][cc] + part[1][j][cc] + cb[((size_t)(b*N_)+w)*M_+cc];
      mraw[(((size_t)(b*N_)+i)*N_+w)*M_ + cc] = f2b(fmaxf(v, 0.f));
    }
  }
  __syncthreads();
  #pragma unroll
  for (int j=0;j<8;j++) acc[j] = (half==0) ? ld<BF>(b_l1, ch) : 0.f;
  for (int k=half*64; k<half*64+64; k++){
    float wv = ld<BF>(W_l1, (size_t)k*M_+ch);
    #pragma unroll
    for (int j=0;j<8;j++) acc[j] += efs[j][k]*wv;
  }
  #pragma unroll
  for (int j=0;j<8;j++) part[half][j][ch] = acc[j];
  __syncthreads();
  for (int idx=t; idx<8*M_; idx+=256){
    int j = idx>>7, cc = idx&127;
    hl[j][cc] = fmaxf(part[0][j][cc] + part[1][j][cc], 0.f);
  }
  __syncthreads();
  if (t < 8 && (w0+t) < valid){
    float s = ld<BF>(b_l2, 0);
    for (int k=0;k<M_;k++) s += hl[t][k]*ld<BF>(W_l2, k);
    s0[((size_t)(b*N_)+i)*N_ + w0 + t] = s;
  }
}

// link round r>=1: s_next[b,i,w] = L( sigmoid(s_prev[b,w,i]) * mraw[b,w,i] )
template<bool BF>
__global__ __launch_bounds__(256)
void k_link(const bf16* mraw, const float* s_prev,
            const void* W_l1, const void* b_l1,
            const void* W_l2, const void* b_l2,
            const int* hn, const int* on, float* s_next, const int* dflag)
{
  if ((*dflag != 0) != BF) return;
  int b = blockIdx.z, i = blockIdx.y, w0 = blockIdx.x*8;
  int valid = hn[b] + on[b];
  if (i >= valid || w0 >= valid) return;
  int t = threadIdx.x, ch = t & 127, half = t >> 7;
  __shared__ float es[8][M_];
  __shared__ float part[2][8][M_];
  __shared__ float hl[8][M_];
  __shared__ float sgj[8];
  if (t < 8){
    int w = w0 + t;
    sgj[t] = (w < valid) ? sigm(s_prev[((size_t)(b*N_)+w)*N_+i]) : 0.f;
  }
  __syncthreads();
  for (int idx=t; idx<8*M_; idx+=256){
    int j = idx>>7, cc = idx&127; int w = w0+j;
    float v = 0.f;
    if (w < valid) v = sgj[j]*b2f(mraw[(((size_t)(b*N_)+w)*N_+i)*M_ + cc]);
    es[j][cc] = v;
  }
  __syncthreads();
  float acc[8];
  #pragma unroll
  for (int j=0;j<8;j++) acc[j] = (half==0) ? ld<BF>(b_l1, ch) : 0.f;
  for (int k=half*64; k<half*64+64; k++){
    float wv = ld<BF>(W_l1, (size_t)k*M_+ch);
    #pragma unroll
    for (int j=0;j<8;j++) acc[j] += es[j][k]*wv;
  }
  #pragma unroll
  for (int j=0;j<8;j++) part[half][j][ch] = acc[j];
  __syncthreads();
  for (int idx=t; idx<8*M_; idx+=256){
    int j = idx>>7, cc = idx&127;
    hl[j][cc] = fmaxf(part[0][j][cc] + part[1][j][cc], 0.f);
  }
  __syncthreads();
  if (t < 8 && (w0+t) < valid){
    float s = ld<BF>(b_l2, 0);
    for (int k=0;k<M_;k++) s += hl[t][k]*ld<BF>(W_l2, k);
    s_next[((size_t)(b*N_)+i)*N_ + w0 + t] = s;
  }
}

// final: pred_adj = s2 (valid block) ; m_sum = sum_w sigmoid(s2)*mraw ; GRU ; readout
template<bool BF>
__global__ __launch_bounds__(128)
void k_final(const bf16* mraw, const float* s2, const float* nf,
             const void* W_ih, const void* b_ih,
             const void* W_hh, const void* b_hh,
             const void* W_ro, const void* b_ro,
             const int* hn, const int* on, void* out, const int* dflag)
{
  if ((*dflag != 0) != BF) return;
  int i = blockIdx.x, b = blockIdx.y;
  int valid = hn[b] + on[b];
  if (i >= valid) return;
  int t = threadIdx.x;  // 128
  __shared__ float sg[N_];
  __shared__ float xsh[M_], hsh[M_], hns[M_];
  const float* srow = s2 + ((size_t)(b*N_)+i)*N_;
  size_t adj = ((size_t)(b*N_)+i)*N_;
  for (int w=t; w<N_; w+=128){
    if (w < valid){
      float v = srow[w];
      st<BF>(out, adj + w, v);
      sg[w] = sigm(v);
    } else sg[w] = 0.f;
  }
  __syncthreads();
  const bf16* mrow = mraw + (((size_t)(b*N_)+i)*N_)*M_;
  float acc = 0.f;
  for (int w=0; w<valid; w++) acc += sg[w]*b2f(mrow[(size_t)w*M_ + t]);
  xsh[t] = acc;
  hsh[t] = nf[((size_t)(b*N_)+i)*M_ + t];
  __syncthreads();
  float gi[3], gh[3];
  #pragma unroll
  for (int g=0; g<3; g++){
    int o = g*M_ + t;
    float a = ld<BF>(b_ih, o), c = ld<BF>(b_hh, o);
    for (int k=0; k<M_; k++){
      a += xsh[k]*ld<BF>(W_ih, (size_t)k*(3*M_)+o);
      c += hsh[k]*ld<BF>(W_hh, (size_t)k*(3*M_)+o);
    }
    gi[g] = a; gh[g] = c;
  }
  float r  = sigm(gi[0] + gh[0]);
  float z  = sigm(gi[1] + gh[1]);
  float nn = tanhf(gi[2] + r*gh[2]);
  float hnew = (1.f - z)*nn + z*hsh[t];
  hns[t] = hnew;
  __syncthreads();
  size_t lab = (size_t)ADJ_SZ + ((size_t)(b*N_)+i)*CL_;
  for (int cls=t; cls<CL_; cls+=128){
    float a = ld<BF>(b_ro, cls);
    for (int k=0; k<M_; k++) a += hns[k]*ld<BF>(W_ro, (size_t)k*CL_+cls);
    st<BF>(out, lab + cls, a);
  }
}

template<bool BF>
static void run_pipeline(void* const* d_in, void* d_out, int out_size,
                         bf16* mraw, float* s_a, float* s_b, float* nf, float* cb,
                         const int* dflag, hipStream_t stream)
{
  const void* edgef = d_in[0];
  const void* nodef = d_in[1];
  const int*  hn    = (const int*)d_in[4];
  const int*  on    = (const int*)d_in[5];
  const void* W_er  = d_in[6];  const void* b_er  = d_in[7];
  const void* W_nr  = d_in[8];  const void* b_nr  = d_in[9];
  const void* W_l1  = d_in[10]; const void* b_l1  = d_in[11];
  const void* W_l2  = d_in[12]; const void* b_l2  = d_in[13];
  const void* W_msg = d_in[14]; const void* b_msg = d_in[15];
  const void* W_ih  = d_in[16]; const void* b_ih  = d_in[17];
  const void* W_hh  = d_in[18]; const void* b_hh  = d_in[19];
  const void* W_ro  = d_in[20]; const void* b_ro  = d_in[21];

  k_zero<BF><<<(out_size+255)/256, 256, 0, stream>>>(d_out, out_size, dflag);
  k_nf_c<BF><<<B_*N_, 128, 0, stream>>>(nodef, W_nr, b_nr, W_msg, b_msg, nf, cb, dflag);
  dim3 g2(N_/8, N_, B_);
  k_ef_mraw_s0<BF><<<g2, 256, 0, stream>>>(edgef, W_er, b_er, W_msg, cb,
                                           W_l1, b_l1, W_l2, b_l2, hn, on, mraw, s_a, dflag);
  k_link<BF><<<g2, 256, 0, stream>>>(mraw, s_a, W_l1, b_l1, W_l2, b_l2, hn, on, s_b, dflag);
  k_link<BF><<<g2, 256, 0, stream>>>(mraw, s_b, W_l1, b_l1, W_l2, b_l2, hn, on, s_a, dflag);
  k_final<BF><<<dim3(N_, B_), 128, 0, stream>>>(mraw, s_a, nf, W_ih, b_ih, W_hh, b_hh,
                                                W_ro, b_ro, hn, on, d_out, dflag);
}

extern "C" void kernel_launch(void* const* d_in, const int* in_sizes, int n_in,
                              void* d_out, int out_size, void* d_ws, size_t ws_size,
                              hipStream_t stream)
{
  char*  ws   = (char*)d_ws;
  bf16*  mraw = (bf16*)ws;                       // 67,108,864 B
  float* s_a  = (float*)(ws + 67108864);         //  1,048,576 B
  float* s_b  = (float*)(ws + 68157440);         //  1,048,576 B
  float* nf   = (float*)(ws + 69206016);         //    524,288 B
  float* cb   = (float*)(ws + 69730304);         //    524,288 B
  int*   dflag= (int*)  (ws + 70254592);         //          4 B

  k_detect<<<1, 64, 0, stream>>>((const unsigned short*)d_in[0], dflag);
  run_pipeline<false>(d_in, d_out, out_size, mraw, s_a, s_b, nf, cb, dflag, stream);
  run_pipeline<true >(d_in, d_out, out_size, mraw, s_a, s_b, nf, cb, dflag, stream);
}

// Round 3
// 561.749 us; speedup vs baseline: 2.1919x; 2.1919x over previous
//
#include <hip/hip_runtime.h>
#include <hip/hip_bf16.h>

// GPNN_HICO: B=4, N=256, EDGE_F=256, MSG=128, LINK_H=128, ROUNDS=3, CLASSES=600
// MFMA version. Algebra:
//  - only the valid[b] x valid[b] block matters
//  - m_raw is round-invariant
//  - e_state_r[b,i,w] = sigmoid(s_{r-1}[b,w,i]) * m_raw[b,w,i]
// Weights are repacked per-launch into MFMA fragment order / transposed order.

#define B_ 4
#define N_ 256
#define EF_ 256
#define M_ 128
#define CL_ 600
#define ADJ_SZ (B_*N_*N_)

typedef __hip_bfloat16 bf16;
typedef short short8 __attribute__((ext_vector_type(8)));
typedef float f32x4 __attribute__((ext_vector_type(4)));

#define MFMA(a,b,c) __builtin_amdgcn_mfma_f32_16x16x32_bf16(a,b,c,0,0,0)

__device__ __forceinline__ float s2f(short s){
  union { unsigned int u; float f; } x; x.u = ((unsigned int)(unsigned short)s) << 16; return x.f;
}
__device__ __forceinline__ bf16 f2b(float f){ return __float2bfloat16(f); }
__device__ __forceinline__ short f2bs(float f){
  bf16 h = __float2bfloat16(f);
  return *reinterpret_cast<short*>(&h);
}
__device__ __forceinline__ float sigm(float x){ return 1.0f/(1.0f+expf(-x)); }

template<bool BF> __device__ __forceinline__ float ld(const void* p, size_t i){
  if (BF) return s2f(((const short*)p)[i]);
  return ((const float*)p)[i];
}
template<bool BF> __device__ __forceinline__ void st(void* p, size_t i, float v){
  if (BF) ((bf16*)p)[i] = f2b(v);
  else    ((float*)p)[i] = v;
}
__device__ __forceinline__ float dot8(short8 w, const float* x){
  float a = 0.f;
  #pragma unroll
  for (int j=0;j<8;j++) a += x[j]*s2f(w[j]);
  return a;
}

// ---- dtype detector (validated in R2): bf16 buffers ~100% sane exponents;
// fp32 read as uint16 ~59%. ----
__global__ __launch_bounds__(64)
void k_detect(const unsigned short* ef, int* flag){
  int t = threadIdx.x;
  int cnt = 0;
  for (int j = 0; j < 64; j++){
    unsigned short u = ef[t*64 + j];
    int e = (u >> 7) & 0xFF;
    cnt += (e >= 96 && e <= 144) ? 1 : 0;
  }
  for (int o = 32; o > 0; o >>= 1) cnt += __shfl_down(cnt, o, 64);
  if (t == 0) *flag = (cnt > 3500) ? 1 : 0;
}

template<bool BF>
__global__ __launch_bounds__(256)
void k_zero(void* out, int n, const int* dflag){
  if ((*dflag != 0) != BF) return;
  int i = blockIdx.x*256 + threadIdx.x;
  if (i < n) st<BF>(out, i, 0.0f);
}

// Repack KxN weight into MFMA B-fragment order:
// dst[(((kk*(N/16)+nt)*64+lane)*8+j] = src[(kk*32+(lane>>4)*8+j)*N + nt*16+(lane&15)]
template<bool BF>
__global__ __launch_bounds__(64)
void k_pack(const void* src, int K, int N, bf16* dst, const int* dflag){
  if ((*dflag != 0) != BF) return;
  int blk = blockIdx.x;
  int n16 = N >> 4;
  int kk = blk / n16, nt = blk % n16;
  int lane = threadIdx.x;
  int k0 = kk*32 + (lane>>4)*8;
  int n  = nt*16 + (lane&15);
  size_t dbase = ((size_t)blk*64 + lane)*8;
  #pragma unroll
  for (int j=0;j<8;j++)
    dst[dbase+j] = f2b(ld<BF>(src, (size_t)(k0+j)*N + n));
}

// transpose KxN -> dst[n*K+k] (bf16)
template<bool BF>
__global__ __launch_bounds__(256)
void k_tr(const void* src, int K, int N, bf16* dst, const int* dflag){
  if ((*dflag != 0) != BF) return;
  int idx = blockIdx.x*256 + threadIdx.x;
  if (idx >= K*N) return;
  int k = idx / N, n = idx % N;
  dst[(size_t)n*K + k] = f2b(ld<BF>(src, idx));
}

// nf[b,v,:] = node @ W_nr + b_nr ; cb[b,v,:] = b_msg + nf @ W_msg[0:128,:]
template<bool BF>
__global__ __launch_bounds__(128)
void k_nf_c(const void* nodef, const bf16* tWnr, const void* b_nr,
            const bf16* tWmsgT, const void* b_msg, float* nf, float* cb,
            const int* dflag)
{
  if ((*dflag != 0) != BF) return;
  int blk = blockIdx.x; int b = blk >> 8; int v = blk & 255;
  int t = threadIdx.x;  // 128
  __shared__ float xs[EF_];
  __shared__ float nfs[M_];
  size_t xrow = ((size_t)(b*N_)+v)*EF_;
  xs[t]     = ld<BF>(nodef, xrow + t);
  xs[t+128] = ld<BF>(nodef, xrow + t + 128);
  __syncthreads();
  float acc = ld<BF>(b_nr, t);
  const short8* wp = (const short8*)(tWnr + (size_t)t*EF_);
  #pragma unroll 4
  for (int k8=0;k8<32;k8++) acc += dot8(wp[k8], &xs[k8*8]);
  nf[((size_t)(b*N_)+v)*M_+t] = acc;
  nfs[t] = acc;
  __syncthreads();
  float acc2 = ld<BF>(b_msg, t);
  const short8* wq = (const short8*)(tWmsgT + (size_t)t*M_);
  #pragma unroll 4
  for (int k8=0;k8<16;k8++) acc2 += dot8(wq[k8], &nfs[k8*8]);
  cb[((size_t)(b*N_)+v)*M_+t] = acc2;
}

// Fused round 0 per (b, i, 32-w tile): MFMA GEMMs.
//   ef = edge @ W_er + b_er
//   mraw = relu(cb[b,w] + ef @ W_msg[128:,:])   (bf16 to ws)
//   s0 = relu(ef @ W_l1 + b_l1) @ W_l2 + b_l2
template<bool BF>
__global__ __launch_bounds__(256)
void k_r0(const void* edgef, const bf16* pWer, const void* b_er,
          const bf16* pWmsgB, const float* cb, const bf16* pWl1,
          const void* b_l1, const void* W_l2, const void* b_l2,
          const int* hn, const int* on, bf16* mraw, float* s0,
          const int* dflag)
{
  if ((*dflag != 0) != BF) return;
  int b = blockIdx.z, i = blockIdx.y, w0 = blockIdx.x*32;
  int valid = hn[b] + on[b];
  if (i >= valid || w0 >= valid) return;
  int t = threadIdx.x;
  __shared__ __attribute__((aligned(16))) bf16 EfsB[32][136];
  __shared__ __attribute__((aligned(16))) char uni[32*264*2]; // Xs bf16[32][264] | hls f32[32][132]
  bf16  (*Xs)[264]  = (bf16(*)[264])uni;
  float (*hls)[132] = (float(*)[132])uni;

  // stage edge rows [32][256]
  {
    int j = t>>3, c = (t&7)*32;
    size_t g = (((size_t)(b*N_)+i)*N_ + (size_t)(w0+j))*EF_ + c;
    if (BF){
      const short8* src = (const short8*)((const short*)edgef + g);
      short8* dst = (short8*)&Xs[j][c];
      #pragma unroll
      for (int u=0;u<4;u++) dst[u] = src[u];
    } else {
      const float* src = (const float*)edgef + g;
      #pragma unroll
      for (int u=0;u<32;u++) Xs[j][c+u] = f2b(src[u]);
    }
  }
  __syncthreads();

  int lane = t & 63, wv = t >> 6;
  int r0 = (wv&1)*16;
  int c0h = wv >> 1;               // column half (0/1), 64 cols each
  int mA = r0 + (lane&15);
  int kq = (lane>>4)*8;
  int qrow = r0 + (lane>>4)*4;

  f32x4 z4 = {0.f,0.f,0.f,0.f};
  f32x4 acc[4] = {z4,z4,z4,z4};
  for (int kk=0;kk<8;kk++){
    short8 a = *(const short8*)&Xs[mA][kk*32 + kq];
    #pragma unroll
    for (int nt=0;nt<4;nt++){
      int gnt = c0h*4 + nt;
      short8 bb = *(const short8*)(pWer + (((size_t)kk*8 + gnt)*64 + lane)*8);
      acc[nt] = MFMA(a, bb, acc[nt]);
    }
  }
  // ef -> LDS bf16 (with bias)
  #pragma unroll
  for (int nt=0;nt<4;nt++){
    int col = c0h*64 + nt*16 + (lane&15);
    float be = ld<BF>(b_er, col);
    #pragma unroll
    for (int r=0;r<4;r++)
      EfsB[qrow+r][col] = f2b(acc[nt][r] + be);
  }
  __syncthreads();

  // GEMM2 (mraw) + GEMM3 (hl), shared A-frags, K=128
  f32x4 am[4] = {z4,z4,z4,z4};
  f32x4 ah[4] = {z4,z4,z4,z4};
  for (int kk=0;kk<4;kk++){
    short8 a = *(const short8*)&EfsB[mA][kk*32 + kq];
    #pragma unroll
    for (int nt=0;nt<4;nt++){
      int gnt = c0h*4 + nt;
      size_t off = (((size_t)kk*8 + gnt)*64 + lane)*8;
      short8 b1 = *(const short8*)(pWmsgB + off);
      am[nt] = MFMA(a, b1, am[nt]);
      short8 b2 = *(const short8*)(pWl1 + off);
      ah[nt] = MFMA(a, b2, ah[nt]);
    }
  }
  // epilogues
  #pragma unroll
  for (int nt=0;nt<4;nt++){
    int col = c0h*64 + nt*16 + (lane&15);
    float bl = ld<BF>(b_l1, col);
    #pragma unroll
    for (int r=0;r<4;r++){
      int row = qrow + r;
      int w = w0 + row;
      float v = am[nt][r] + cb[((size_t)(b*N_)+w)*M_ + col];
      mraw[(((size_t)(b*N_)+i)*N_ + w)*M_ + col] = f2b(fmaxf(v, 0.f));
      hls[row][col] = fmaxf(ah[nt][r] + bl, 0.f);
    }
  }
  __syncthreads();
  // s0 GEMV: 8 lanes per row
  {
    int row = t>>3, seg = t&7;
    float p = 0.f;
    #pragma unroll
    for (int k=0;k<16;k++) p += hls[row][seg*16+k] * ld<BF>(W_l2, seg*16+k);
    p += __shfl_down(p, 4, 8);
    p += __shfl_down(p, 2, 8);
    p += __shfl_down(p, 1, 8);
    if (seg==0 && (w0+row) < valid)
      s0[((size_t)(b*N_)+i)*N_ + w0 + row] = p + ld<BF>(b_l2, 0);
  }
}

// link round: s_next[b,i,w] = relu(sig(s_prev[b,w,i])*mraw[b,w,i,:] @ W_l1 + b_l1) @ W_l2 + b_l2
template<bool BF>
__global__ __launch_bounds__(256)
void k_link2(const bf16* mraw, const float* s_prev, const bf16* pWl1,
             const void* b_l1, const void* W_l2, const void* b_l2,
             const int* hn, const int* on, float* s_next, const int* dflag)
{
  if ((*dflag != 0) != BF) return;
  int b = blockIdx.z, i = blockIdx.y, w0 = blockIdx.x*32;
  int valid = hn[b] + on[b];
  if (i >= valid || w0 >= valid) return;
  int t = threadIdx.x;
  __shared__ __attribute__((aligned(16))) bf16 EsB[32][136];
  __shared__ __attribute__((aligned(16))) float hls[32][132];
  __shared__ float sg[32];
  if (t < 32){
    int w = w0 + t;
    sg[t] = (w < valid) ? sigm(s_prev[((size_t)(b*N_)+w)*N_ + i]) : 0.f;
  }
  __syncthreads();
  {
    int j = t>>3, c = (t&7)*16;
    const short* src = (const short*)mraw + (((size_t)(b*N_)+(size_t)(w0+j))*N_ + i)*M_;
    float s = sg[j];
    #pragma unroll
    for (int u=0;u<2;u++){
      short8 v = *(const short8*)(src + c + u*8);
      short8 o;
      #pragma unroll
      for (int e=0;e<8;e++) o[e] = f2bs(s2f(v[e])*s);
      *(short8*)&EsB[j][c+u*8] = o;
    }
  }
  __syncthreads();

  int lane = t & 63, wv = t >> 6;
  int r0 = (wv&1)*16;
  int c0h = wv >> 1;
  int mA = r0 + (lane&15);
  int kq = (lane>>4)*8;
  int qrow = r0 + (lane>>4)*4;

  f32x4 z4 = {0.f,0.f,0.f,0.f};
  f32x4 ah[4] = {z4,z4,z4,z4};
  for (int kk=0;kk<4;kk++){
    short8 a = *(const short8*)&EsB[mA][kk*32 + kq];
    #pragma unroll
    for (int nt=0;nt<4;nt++){
      int gnt = c0h*4 + nt;
      short8 b2 = *(const short8*)(pWl1 + (((size_t)kk*8 + gnt)*64 + lane)*8);
      ah[nt] = MFMA(a, b2, ah[nt]);
    }
  }
  #pragma unroll
  for (int nt=0;nt<4;nt++){
    int col = c0h*64 + nt*16 + (lane&15);
    float bl = ld<BF>(b_l1, col);
    #pragma unroll
    for (int r=0;r<4;r++)
      hls[qrow+r][col] = fmaxf(ah[nt][r] + bl, 0.f);
  }
  __syncthreads();
  {
    int row = t>>3, seg = t&7;
    float p = 0.f;
    #pragma unroll
    for (int k=0;k<16;k++) p += hls[row][seg*16+k] * ld<BF>(W_l2, seg*16+k);
    p += __shfl_down(p, 4, 8);
    p += __shfl_down(p, 2, 8);
    p += __shfl_down(p, 1, 8);
    if (seg==0 && (w0+row) < valid)
      s_next[((size_t)(b*N_)+i)*N_ + w0 + row] = p + ld<BF>(b_l2, 0);
  }
}

// final: pred_adj = s2 ; m_sum = sum_w sig(s2)*mraw ; GRU ; readout
template<bool BF>
__global__ __launch_bounds__(128)
void k_final(const bf16* mraw, const float* s2, const float* nf,
             const bf16* tWih, const void* b_ih,
             const bf16* tWhh, const void* b_hh,
             const bf16* tWro, const void* b_ro,
             const int* hn, const int* on, void* out, const int* dflag)
{
  if ((*dflag != 0) != BF) return;
  int i = blockIdx.x, b = blockIdx.y;
  int valid = hn[b] + on[b];
  if (i >= valid) return;
  int t = threadIdx.x;  // 128
  __shared__ float sgs[N_];
  __shared__ float xsh[M_], hsh[M_], hns[M_];
  const float* srow = s2 + ((size_t)(b*N_)+i)*N_;
  size_t adj = ((size_t)(b*N_)+i)*N_;
  for (int w=t; w<N_; w+=128){
    if (w < valid){
      float v = srow[w];
      st<BF>(out, adj + w, v);
      sgs[w] = sigm(v);
    } else sgs[w] = 0.f;
  }
  __syncthreads();
  const short* mrow = (const short*)mraw + (((size_t)(b*N_)+i)*N_)*M_;
  float acc = 0.f;
  for (int w=0; w<valid; w++) acc += sgs[w]*s2f(mrow[(size_t)w*M_ + t]);
  xsh[t] = acc;
  hsh[t] = nf[((size_t)(b*N_)+i)*M_ + t];
  __syncthreads();
  float gi[3], gh[3];
  #pragma unroll
  for (int g=0; g<3; g++){
    int o = g*M_ + t;
    float a = ld<BF>(b_ih, o), c = ld<BF>(b_hh, o);
    const short8* wi = (const short8*)(tWih + (size_t)o*M_);
    const short8* wh = (const short8*)(tWhh + (size_t)o*M_);
    #pragma unroll 4
    for (int k8=0;k8<16;k8++){
      a += dot8(wi[k8], &xsh[k8*8]);
      c += dot8(wh[k8], &hsh[k8*8]);
    }
    gi[g] = a; gh[g] = c;
  }
  float r  = sigm(gi[0] + gh[0]);
  float z  = sigm(gi[1] + gh[1]);
  float nn = tanhf(gi[2] + r*gh[2]);
  float hnew = (1.f - z)*nn + z*hsh[t];
  hns[t] = hnew;
  __syncthreads();
  size_t lab = (size_t)ADJ_SZ + ((size_t)(b*N_)+i)*CL_;
  for (int cls=t; cls<CL_; cls+=128){
    float a = ld<BF>(b_ro, cls);
    const short8* wr = (const short8*)(tWro + (size_t)cls*M_);
    #pragma unroll 4
    for (int k8=0;k8<16;k8++) a += dot8(wr[k8], &hns[k8*8]);
    st<BF>(out, lab + cls, a);
  }
}

template<bool BF>
static void run_pipeline(void* const* d_in, void* d_out, int out_size,
                         char* ws, const int* dflag, hipStream_t stream)
{
  const void* edgef = d_in[0];
  const void* nodef = d_in[1];
  const int*  hn    = (const int*)d_in[4];
  const int*  on    = (const int*)d_in[5];
  const void* W_er  = d_in[6];  const void* b_er  = d_in[7];
  const void* W_nr  = d_in[8];  const void* b_nr  = d_in[9];
  const void* W_l1  = d_in[10]; const void* b_l1  = d_in[11];
  const void* W_l2  = d_in[12]; const void* b_l2  = d_in[13];
  const void* W_msg = d_in[14]; const void* b_msg = d_in[15];
  const void* W_ih  = d_in[16]; const void* b_ih  = d_in[17];
  const void* W_hh  = d_in[18]; const void* b_hh  = d_in[19];
  const void* W_ro  = d_in[20]; const void* b_ro  = d_in[21];

  bf16*  mraw   = (bf16*) (ws);
  float* s_a    = (float*)(ws + 67108864);
  float* s_b    = (float*)(ws + 68157440);
  float* nf     = (float*)(ws + 69206016);
  float* cb     = (float*)(ws + 69730304);
  bf16*  pWer   = (bf16*) (ws + 70254592);
  bf16*  pWmsgB = (bf16*) (ws + 70320128);
  bf16*  pWl1   = (bf16*) (ws + 70352896);
  bf16*  tWnr   = (bf16*) (ws + 70385664);
  bf16*  tWmsgT = (bf16*) (ws + 70451200);
  bf16*  tWih   = (bf16*) (ws + 70483968);
  bf16*  tWhh   = (bf16*) (ws + 70582272);
  bf16*  tWro   = (bf16*) (ws + 70680576);

  const void* W_msgB = BF ? (const void*)((const bf16*)W_msg + 128*M_)
                          : (const void*)((const float*)W_msg + 128*M_);

  k_zero<BF><<<(out_size+255)/256, 256, 0, stream>>>(d_out, out_size, dflag);
  // weight repacks
  k_pack<BF><<<64, 64, 0, stream>>>(W_er, 256, 128, pWer, dflag);
  k_pack<BF><<<32, 64, 0, stream>>>(W_msgB, 128, 128, pWmsgB, dflag);
  k_pack<BF><<<32, 64, 0, stream>>>(W_l1, 128, 128, pWl1, dflag);
  k_tr<BF><<<128, 256, 0, stream>>>(W_nr, 256, 128, tWnr, dflag);
  k_tr<BF><<<64, 256, 0, stream>>>(W_msg, 128, 128, tWmsgT, dflag);
  k_tr<BF><<<192, 256, 0, stream>>>(W_ih, 128, 384, tWih, dflag);
  k_tr<BF><<<192, 256, 0, stream>>>(W_hh, 128, 384, tWhh, dflag);
  k_tr<BF><<<300, 256, 0, stream>>>(W_ro, 128, 600, tWro, dflag);

  k_nf_c<BF><<<B_*N_, 128, 0, stream>>>(nodef, tWnr, b_nr, tWmsgT, b_msg, nf, cb, dflag);
  dim3 g2(N_/32, N_, B_);
  k_r0<BF><<<g2, 256, 0, stream>>>(edgef, pWer, b_er, pWmsgB, cb, pWl1,
                                   b_l1, W_l2, b_l2, hn, on, mraw, s_a, dflag);
  k_link2<BF><<<g2, 256, 0, stream>>>(mraw, s_a, pWl1, b_l1, W_l2, b_l2, hn, on, s_b, dflag);
  k_link2<BF><<<g2, 256, 0, stream>>>(mraw, s_b, pWl1, b_l1, W_l2, b_l2, hn, on, s_a, dflag);
  k_final<BF><<<dim3(N_, B_), 128, 0, stream>>>(mraw, s_a, nf, tWih, b_ih, tWhh, b_hh,
                                                tWro, b_ro, hn, on, d_out, dflag);
}

extern "C" void kernel_launch(void* const* d_in, const int* in_sizes, int n_in,
                              void* d_out, int out_size, void* d_ws, size_t ws_size,
                              hipStream_t stream)
{
  char* ws = (char*)d_ws;
  int* dflag = (int*)(ws + 70834176);

  k_detect<<<1, 64, 0, stream>>>((const unsigned short*)d_in[0], dflag);
  run_pipeline<false>(d_in, d_out, out_size, ws, dflag, stream);
  run_pipeline<true >(d_in, d_out, out_size, ws, dflag, stream);
}